// Round 12
// baseline (135.033 us; speedup 1.0000x reference)
//
#include <hip/hip_runtime.h>
#include <cstdint>

#define MDIM 2048
#define KDIM 1024
#define CDIM 8192
#define BM 256
#define BN 128
#define BK 32
#define NT (KDIM / BK)      // 32 K-tiles
#define NCHUNK (CDIM / 64)  // 128 chunks of 64 cols
#define SLOT 24576          // A 16KB + B 8KB per K-tile
#define NSLOT 3             // 72 KB LDS -> 2 blocks/CU
#define CVT_BLOCKS 1280     // grid-stride over 5120 row-pairs, 4 iters

typedef __attribute__((ext_vector_type(8))) __bf16 bf16x8;
typedef __attribute__((ext_vector_type(4))) float f32x4;
typedef __attribute__((ext_vector_type(8))) unsigned short ushort8;

// ---------- helpers ----------
__device__ __forceinline__ unsigned short f2bf(float f) {
  unsigned u = __float_as_uint(f);
  u += 0x7fffu + ((u >> 16) & 1u);   // RNE
  return (unsigned short)(u >> 16);
}

__device__ __forceinline__ void async_ld16(const void* g, void* l) {
  __builtin_amdgcn_global_load_lds(
      (__attribute__((address_space(1))) void*)(g),
      (__attribute__((address_space(3))) void*)(l),
      16, 0, 0);
}

// ---------- K0: convert x & centroids to bf16 (16B stores); c2 = ||c||^2 ----------
__global__ __launch_bounds__(256) void convert_all(const float* __restrict__ x,
                                                   const float* __restrict__ cent,
                                                   unsigned short* __restrict__ xb,
                                                   unsigned short* __restrict__ cb,
                                                   float* __restrict__ c2) {
  const int t = threadIdx.x;
  const int wv = t >> 6, lane = t & 63;
  const int rsel = wv >> 1;        // which row of the pair
  const int half = wv & 1;         // which half of the row
  const int eidx = half * 64 + lane;   // ushort8 index within row (0..127)
  __shared__ float red[4];
  for (int p = blockIdx.x; p < (MDIM + CDIM) / 2; p += CVT_BLOCKS) {
    const int row = p * 2 + rsel;
    const bool isc = row >= MDIM;
    const float* srcrow = isc ? (cent + (size_t)(row - MDIM) * KDIM)
                              : (x + (size_t)row * KDIM);
    const float4* src = (const float4*)srcrow + eidx * 2;
    const float4 v0 = src[0], v1 = src[1];
    ushort8 o;
    o[0] = f2bf(v0.x); o[1] = f2bf(v0.y); o[2] = f2bf(v0.z); o[3] = f2bf(v0.w);
    o[4] = f2bf(v1.x); o[5] = f2bf(v1.y); o[6] = f2bf(v1.z); o[7] = f2bf(v1.w);
    if (!isc) {
      ((ushort8*)(xb + (size_t)row * KDIM))[eidx] = o;
    } else {
      ((ushort8*)(cb + (size_t)(row - MDIM) * KDIM))[eidx] = o;
      float pq = v0.x * v0.x + v0.y * v0.y + v0.z * v0.z + v0.w * v0.w
               + v1.x * v1.x + v1.y * v1.y + v1.z * v1.z + v1.w * v1.w;
      for (int d = 32; d; d >>= 1) pq += __shfl_down(pq, d, 64);
      if (lane == 0) red[wv] = pq;
    }
    __syncthreads();
    if (isc && half == 0 && lane == 0)
      c2[row - MDIM] = red[wv] + red[wv + 1];
    __syncthreads();   // red[] reused next iteration
  }
}

// ---------- K1: 256x128-tile bf16 MFMA GEMM, 2 blocks/CU, ring-3, counted vmcnt ----------
// R11 lever pushed further: 512 blocks of 8 waves (4x2, 64x64/wave) -> TWO independent
// barrier domains per CU (72KB LDS each). While one block stalls at its barrier/vmcnt,
// the other block's waves keep the MFMA + LDS pipes busy (m114 mechanism).
// Same swizzle (conflict-free), counted vmcnt (3->0 tail), XCD bn-slice remap.
// s = 2*x.c - c2, fused per-64col online softmax/argmax epilogue.
__global__ __launch_bounds__(512, 4) void gemm_reduce(
    const unsigned short* __restrict__ Ab, const unsigned short* __restrict__ Bb,
    const float* __restrict__ c2,
    float* __restrict__ pm, float* __restrict__ pl, int* __restrict__ pidx) {
  __shared__ __align__(16) char lds[NSLOT * SLOT];   // 72 KB

  const int tid = threadIdx.x;
  const int wave = tid >> 6, lane = tid & 63;
  const int wm = wave >> 1, wn = wave & 1;        // 4 x 2 wave grid
  const int quad = lane >> 4, c16 = lane & 15;

  // XCD-chunked block remap (bijective): XCD k = id&7 owns bn in [k*8,k*8+8) x all bm.
  // Per-XCD working set: B-slice 2MB (L2-hot) + A 4MB. Consecutive j share bm.
  const int id = blockIdx.y * gridDim.x + blockIdx.x;      // 0..511
  const int k = id & 7, j = id >> 3;                       // XCD, slot-in-XCD (0..63)
  const int bm = j >> 3;                                   // 0..7
  const int bn = k * 8 + (j & 7);                          // 0..63
  const int bmBase = bm * BM, bnBase = bn * BN;

  // ---- staging: thread stages A-chunks {tid, tid+512} + B-chunk tid (16B each) ----
  // LDS chunk i holds logical chunk (row = i>>2, pos ^ s(row)), s(row) = (row>>1)&3;
  // conflict-free swizzle, LDS dest linear (rule #21). B rows share r1/c1 (tid<512).
  const int r1 = tid >> 2, c1 = (tid & 3) ^ ((r1 >> 1) & 3);
  const int r2 = (tid + 512) >> 2, c2s = (tid & 3) ^ ((r2 >> 1) & 3);
  const char* Ag1 = (const char*)(Ab + (size_t)(bmBase + r1) * KDIM + c1 * 8);
  const char* Ag2 = (const char*)(Ab + (size_t)(bmBase + r2) * KDIM + c2s * 8);
  const char* Bg1 = (const char*)(Bb + (size_t)(bnBase + r1) * KDIM + c1 * 8);
  const int wbyte = wave * 1024;                  // wave-uniform LDS base (lane*16 implicit)

  // ---- fragment read offsets (swizzled): logical (row, quad) lives at chunk quad^s(row) ----
  int aoff[4], boff[4];
#pragma unroll
  for (int mt = 0; mt < 4; ++mt) {
    const int row = wm * 64 + mt * 16 + c16;
    aoff[mt] = row * 64 + ((quad ^ ((row >> 1) & 3)) * 16);
  }
#pragma unroll
  for (int nt = 0; nt < 4; ++nt) {
    const int col = wn * 64 + nt * 16 + c16;
    boff[nt] = 16384 + col * 64 + ((quad ^ ((col >> 1) & 3)) * 16);
  }

  f32x4 acc[4][4] = {};

#define STAGE(T)                                          \
  {                                                       \
    const int _ko = (T) * (BK * 2);                       \
    char* _sb = &lds[((T) % NSLOT) * SLOT];               \
    async_ld16(Ag1 + _ko, _sb + wbyte);                   \
    async_ld16(Ag2 + _ko, _sb + 8192 + wbyte);            \
    async_ld16(Bg1 + _ko, _sb + 16384 + wbyte);           \
  }

  // prologue: 2 tiles in flight (6 loads/thread)
  STAGE(0); STAGE(1);

#pragma unroll 1
  for (int t = 0; t < NT; ++t) {
    // entry gate: tile t landed (tile t+1's 3 loads may stay in flight)
    if (t < NT - 1) asm volatile("s_waitcnt vmcnt(3)" ::: "memory");
    else            asm volatile("s_waitcnt vmcnt(0)" ::: "memory");
    __builtin_amdgcn_s_barrier();                 // all waves: tile t landed, t-1 reads done
    __builtin_amdgcn_sched_barrier(0);            // pin reads/STAGE below the barrier

    if (t < NT - 2) STAGE(t + 2);                 // into slot (t-1)%3: freed by this barrier

    const char* sb = &lds[(t % NSLOT) * SLOT];
    bf16x8 a[4], b[4];
#pragma unroll
    for (int nt = 0; nt < 4; ++nt) b[nt] = *(const bf16x8*)(sb + boff[nt]);
#pragma unroll
    for (int mt = 0; mt < 4; ++mt) a[mt] = *(const bf16x8*)(sb + aoff[mt]);

    // no explicit lgkm drain: compiler inserts incremental lgkmcnt(N) per dependency
    __builtin_amdgcn_s_setprio(1);
#pragma unroll
    for (int mt = 0; mt < 4; ++mt)
#pragma unroll
      for (int nt = 0; nt < 4; ++nt)
        acc[mt][nt] = __builtin_amdgcn_mfma_f32_16x16x32_bf16(a[mt], b[nt], acc[mt][nt], 0, 0, 0);
    __builtin_amdgcn_s_setprio(0);
  }
#undef STAGE

  // Epilogue: C/D layout: col = lane&15, row = quad*4 + reg (verified convention).
  const int colbase = bnBase + wn * 64;
  float c2v[4];
#pragma unroll
  for (int nt = 0; nt < 4; ++nt) c2v[nt] = c2[colbase + nt * 16 + c16];

  const int chunk = bn * 2 + wn;
#pragma unroll
  for (int mt = 0; mt < 4; ++mt) {
#pragma unroll
    for (int r = 0; r < 4; ++r) {
      float sv[4];
#pragma unroll
      for (int nt = 0; nt < 4; ++nt) sv[nt] = 2.0f * acc[mt][nt][r] - c2v[nt];
      float m = sv[0];
      int idx = colbase + c16;
#pragma unroll
      for (int nt = 1; nt < 4; ++nt) {
        if (sv[nt] > m) { m = sv[nt]; idx = colbase + nt * 16 + c16; }
      }
      float l = 0.f;
#pragma unroll
      for (int nt = 0; nt < 4; ++nt) l += __expf(sv[nt] - m);
      for (int d = 1; d < 16; d <<= 1) {
        float om = __shfl_xor(m, d, 64);
        float ol = __shfl_xor(l, d, 64);
        int oi = __shfl_xor(idx, d, 64);
        float M = fmaxf(m, om);
        l = l * __expf(m - M) + ol * __expf(om - M);
        idx = (om > m || (om == m && oi < idx)) ? oi : idx;
        m = M;
      }
      if (c16 == 0) {
        const int row = bmBase + wm * 64 + mt * 16 + quad * 4 + r;
        pm[(size_t)row * NCHUNK + chunk] = m;
        pl[(size_t)row * NCHUNK + chunk] = l;
        pidx[(size_t)row * NCHUNK + chunk] = idx;
      }
    }
  }
}

// ---------- K2: per-row combine — single wave, 2 chunks/lane, no LDS ----------
__global__ __launch_bounds__(64) void combine_kernel(
    const float* __restrict__ pm, const float* __restrict__ pl,
    const int* __restrict__ pidx, const float* __restrict__ x,
    const float* __restrict__ cent, const float* __restrict__ c2,
    const int* __restrict__ y,
    float* __restrict__ loss_part, float* __restrict__ corr_part) {
  const int row = blockIdx.x, t = threadIdx.x;  // t = lane, 0..63
  const int yc = y[row];
  const size_t base = (size_t)row * NCHUNK;

  const float m0 = pm[base + t],      l0 = pl[base + t];
  const float m1 = pm[base + t + 64], l1 = pl[base + t + 64];
  const int   i0 = pidx[base + t],    i1 = pidx[base + t + 64];
  float m = fmaxf(m0, m1);
  float l = l0 * __expf(m0 - m) + l1 * __expf(m1 - m);
  int idx = (m1 > m0) ? i1 : i0;     // tie keeps lower index (i0 < i1 always)

  const float4* xa = (const float4*)(x + (size_t)row * KDIM) + t * 4;
  const float4* ca = (const float4*)(cent + (size_t)yc * KDIM) + t * 4;
  float dot = 0.f;
#pragma unroll
  for (int j = 0; j < 4; ++j) {
    const float4 a = xa[j], b = ca[j];
    dot += a.x * b.x + a.y * b.y + a.z * b.z + a.w * b.w;
  }

  for (int d = 1; d < 64; d <<= 1) {
    const float om = __shfl_xor(m, d, 64);
    const float ol = __shfl_xor(l, d, 64);
    const int oi = __shfl_xor(idx, d, 64);
    const float od = __shfl_xor(dot, d, 64);
    const float M = fmaxf(m, om);
    l = l * __expf(m - M) + ol * __expf(om - M);
    idx = (om > m || (om == m && oi < idx)) ? oi : idx;
    m = M;
    dot += od;
  }
  if (t == 0) {
    const float sy = 2.0f * dot - c2[yc];
    loss_part[row] = __logf(l) + m - sy;
    corr_part[row] = (idx == yc) ? 1.f : 0.f;
  }
}

// ---------- K3: finalize means ----------
__global__ __launch_bounds__(256) void finalize(const float* __restrict__ loss_part,
                                                const float* __restrict__ corr_part,
                                                float* __restrict__ out) {
  const int t = threadIdx.x;
  float s0 = 0.f, s1 = 0.f;
  for (int i = t; i < MDIM; i += 256) { s0 += loss_part[i]; s1 += corr_part[i]; }
  for (int d = 32; d; d >>= 1) {
    s0 += __shfl_down(s0, d, 64);
    s1 += __shfl_down(s1, d, 64);
  }
  __shared__ float r0[4], r1[4];
  if ((t & 63) == 0) { r0[t >> 6] = s0; r1[t >> 6] = s1; }
  __syncthreads();
  if (t == 0) {
    out[0] = (r0[0] + r0[1] + r0[2] + r0[3]) * (1.0f / MDIM);
    out[1] = (r1[0] + r1[1] + r1[2] + r1[3]) * (1.0f / MDIM);
  }
}

// ---------- launch ----------
extern "C" void kernel_launch(void* const* d_in, const int* in_sizes, int n_in,
                              void* d_out, int out_size, void* d_ws, size_t ws_size,
                              hipStream_t stream) {
  const float* x = (const float*)d_in[0];
  const int* y = (const int*)d_in[1];
  const float* cent = (const float*)d_in[2];
  float* out = (float*)d_out;

  char* ws = (char*)d_ws;
  const size_t OFF_XB = 0;                                   // 4 MB
  const size_t OFF_CB = OFF_XB + (size_t)MDIM * KDIM * 2;    // 16 MB
  const size_t OFF_C2 = OFF_CB + (size_t)CDIM * KDIM * 2;    // 32 KB
  const size_t OFF_PM = OFF_C2 + (size_t)CDIM * 4;           // 1 MB
  const size_t OFF_PL = OFF_PM + (size_t)NCHUNK * MDIM * 4;  // 1 MB
  const size_t OFF_PI = OFF_PL + (size_t)NCHUNK * MDIM * 4;  // 1 MB
  const size_t OFF_LP = OFF_PI + (size_t)NCHUNK * MDIM * 4;  // 8 KB
  const size_t OFF_CP = OFF_LP + (size_t)MDIM * 4;           // 8 KB
  const size_t NEED = OFF_CP + (size_t)MDIM * 4;
  if (ws_size < NEED) return;

  unsigned short* xb = (unsigned short*)(ws + OFF_XB);
  unsigned short* cb = (unsigned short*)(ws + OFF_CB);
  float* c2 = (float*)(ws + OFF_C2);
  float* pm = (float*)(ws + OFF_PM);
  float* pl = (float*)(ws + OFF_PL);
  int* pidx = (int*)(ws + OFF_PI);
  float* loss_part = (float*)(ws + OFF_LP);
  float* corr_part = (float*)(ws + OFF_CP);

  convert_all<<<CVT_BLOCKS, 256, 0, stream>>>(x, cent, xb, cb, c2);
  gemm_reduce<<<dim3(CDIM / BN, MDIM / BM), 512, 0, stream>>>(xb, cb, c2, pm, pl, pidx);
  combine_kernel<<<MDIM, 64, 0, stream>>>(pm, pl, pidx, x, cent, c2, y, loss_part, corr_part);
  finalize<<<1, 256, 0, stream>>>(loss_part, corr_part, out);
}

// Round 13
// 132.508 us; speedup vs baseline: 1.0191x; 1.0191x over previous
//
#include <hip/hip_runtime.h>
#include <cstdint>

#define MDIM 2048
#define KDIM 1024
#define CDIM 8192
#define BM 256
#define BN 256
#define BK 32
#define NT (KDIM / BK)      // 32 K-tiles
#define NCHUNK (CDIM / 64)  // 128 chunks of 64 cols
#define CVT_BLOCKS 1280     // grid-stride over 5120 row-pairs, 4 iters

typedef __attribute__((ext_vector_type(8))) __bf16 bf16x8;
typedef __attribute__((ext_vector_type(4))) float f32x4;
typedef __attribute__((ext_vector_type(8))) unsigned short ushort8;

// ---------- helpers ----------
__device__ __forceinline__ unsigned short f2bf(float f) {
  unsigned u = __float_as_uint(f);
  u += 0x7fffu + ((u >> 16) & 1u);   // RNE
  return (unsigned short)(u >> 16);
}

__device__ __forceinline__ void async_ld16(const void* g, void* l) {
  __builtin_amdgcn_global_load_lds(
      (__attribute__((address_space(1))) void*)(g),
      (__attribute__((address_space(3))) void*)(l),
      16, 0, 0);
}

// ---------- K0: convert x & centroids to bf16 (16B stores); c2 = ||c||^2 ----------
__global__ __launch_bounds__(256) void convert_all(const float* __restrict__ x,
                                                   const float* __restrict__ cent,
                                                   unsigned short* __restrict__ xb,
                                                   unsigned short* __restrict__ cb,
                                                   float* __restrict__ c2) {
  const int t = threadIdx.x;
  const int wv = t >> 6, lane = t & 63;
  const int rsel = wv >> 1;        // which row of the pair
  const int half = wv & 1;         // which half of the row
  const int eidx = half * 64 + lane;   // ushort8 index within row (0..127)
  __shared__ float red[4];
  for (int p = blockIdx.x; p < (MDIM + CDIM) / 2; p += CVT_BLOCKS) {
    const int row = p * 2 + rsel;
    const bool isc = row >= MDIM;
    const float* srcrow = isc ? (cent + (size_t)(row - MDIM) * KDIM)
                              : (x + (size_t)row * KDIM);
    const float4* src = (const float4*)srcrow + eidx * 2;
    const float4 v0 = src[0], v1 = src[1];
    ushort8 o;
    o[0] = f2bf(v0.x); o[1] = f2bf(v0.y); o[2] = f2bf(v0.z); o[3] = f2bf(v0.w);
    o[4] = f2bf(v1.x); o[5] = f2bf(v1.y); o[6] = f2bf(v1.z); o[7] = f2bf(v1.w);
    if (!isc) {
      ((ushort8*)(xb + (size_t)row * KDIM))[eidx] = o;
    } else {
      ((ushort8*)(cb + (size_t)(row - MDIM) * KDIM))[eidx] = o;
      float pq = v0.x * v0.x + v0.y * v0.y + v0.z * v0.z + v0.w * v0.w
               + v1.x * v1.x + v1.y * v1.y + v1.z * v1.z + v1.w * v1.w;
      for (int d = 32; d; d >>= 1) pq += __shfl_down(pq, d, 64);
      if (lane == 0) red[wv] = pq;
    }
    __syncthreads();
    if (isc && half == 0 && lane == 0)
      c2[row - MDIM] = red[wv] + red[wv + 1];
    __syncthreads();   // red[] reused next iteration
  }
}

// ---------- K1: 256x256-tile bf16 MFMA GEMM, 16 waves (4x4), 4-slot ring ----------
// Best verified configuration (R11): 16 waves x 64x64 per-wave tile, 4 waves/SIMD
// (wave-level read/MFMA overlap, m114 mechanism), ring-4 depth-3 prefetch, counted
// vmcnt (4/2/0 tail), conflict-free swizzle, XCD bn-slice remap (FETCH 25MB).
// Staging: 1 A-chunk + 1 B-chunk (16B) per thread per tile.
// s = 2*x.c - c2, fused per-64col online softmax/argmax epilogue.
__global__ __launch_bounds__(1024, 4) void gemm_reduce(
    const unsigned short* __restrict__ Ab, const unsigned short* __restrict__ Bb,
    const float* __restrict__ c2,
    float* __restrict__ pm, float* __restrict__ pl, int* __restrict__ pidx) {
  __shared__ __align__(16) char lds[4 * 32768];   // 128 KB

  const int tid = threadIdx.x;
  const int wave = tid >> 6, lane = tid & 63;
  const int wm = wave >> 2, wn = wave & 3;        // 4 x 4 wave grid
  const int quad = lane >> 4, c16 = lane & 15;

  // XCD-chunked block remap (bijective): XCD k = id&7 owns bn in [k*4,k*4+4) x all bm.
  const int id = blockIdx.y * gridDim.x + blockIdx.x;      // 0..255
  const int k = id & 7, j = id >> 3;
  const int bm = j >> 2;                                   // 0..7
  const int bn = k * 4 + (j & 3);                          // 0..31
  const int bmBase = bm * BM, bnBase = bn * BN;

  // ---- staging: thread stages A-chunk tid and B-chunk tid (16B each) per tile ----
  // LDS chunk i holds logical chunk (row = i>>2, pos ^ s(row)), s(row) = (row>>1)&3;
  // conflict-free swizzle, LDS dest linear (rule #21).
  const int r1 = tid >> 2, c1 = (tid & 3) ^ ((r1 >> 1) & 3);
  const char* Ag1 = (const char*)(Ab + (size_t)(bmBase + r1) * KDIM + c1 * 8);
  const char* Bg1 = (const char*)(Bb + (size_t)(bnBase + r1) * KDIM + c1 * 8);
  const int wbyte = wave * 1024;                  // wave-uniform LDS base (lane*16 implicit)

  // ---- fragment read offsets (swizzled): logical (row, quad) lives at chunk quad^s(row) ----
  int aoff[4], boff[4];
#pragma unroll
  for (int mt = 0; mt < 4; ++mt) {
    const int row = wm * 64 + mt * 16 + c16;
    aoff[mt] = row * 64 + ((quad ^ ((row >> 1) & 3)) * 16);
  }
#pragma unroll
  for (int nt = 0; nt < 4; ++nt) {
    const int col = wn * 64 + nt * 16 + c16;
    boff[nt] = col * 64 + ((quad ^ ((col >> 1) & 3)) * 16);
  }

  f32x4 acc[4][4] = {};

#define STAGE(T)                                          \
  {                                                       \
    const int _ko = (T) * (BK * 2);                       \
    char* _sb = &lds[((T) & 3) * 32768];                  \
    async_ld16(Ag1 + _ko, _sb + wbyte);                   \
    async_ld16(Bg1 + _ko, _sb + 16384 + wbyte);           \
  }

  // prologue: 3 tiles in flight (6 loads/thread)
  STAGE(0); STAGE(1); STAGE(2);

#pragma unroll 1
  for (int t = 0; t < NT; ++t) {
    // tile t landed when all but the newest 2 tiles (4 loads) retired; tail 4->2->0
    if (t < NT - 2)       asm volatile("s_waitcnt vmcnt(4)" ::: "memory");
    else if (t == NT - 2) asm volatile("s_waitcnt vmcnt(2)" ::: "memory");
    else                  asm volatile("s_waitcnt vmcnt(0)" ::: "memory");
    __builtin_amdgcn_s_barrier();                 // all waves: tile t landed, t-1 reads done
    __builtin_amdgcn_sched_barrier(0);            // pin reads/STAGE below the barrier

    if (t < NT - 3) STAGE(t + 3);                 // into slot (t-1)&3: freed by this barrier

    const char* sb = &lds[(t & 3) * 32768];
    bf16x8 a[4], b[4];
#pragma unroll
    for (int nt = 0; nt < 4; ++nt) b[nt] = *(const bf16x8*)(sb + 16384 + boff[nt]);
#pragma unroll
    for (int mt = 0; mt < 4; ++mt) a[mt] = *(const bf16x8*)(sb + aoff[mt]);

    // no explicit lgkm drain: compiler inserts incremental lgkmcnt(N) per dependency
    __builtin_amdgcn_s_setprio(1);
#pragma unroll
    for (int mt = 0; mt < 4; ++mt)
#pragma unroll
      for (int nt = 0; nt < 4; ++nt)
        acc[mt][nt] = __builtin_amdgcn_mfma_f32_16x16x32_bf16(a[mt], b[nt], acc[mt][nt], 0, 0, 0);
    __builtin_amdgcn_s_setprio(0);
  }
#undef STAGE

  // Epilogue: C/D layout: col = lane&15, row = quad*4 + reg (verified convention).
  const int colbase = bnBase + wn * 64;
  float c2v[4];
#pragma unroll
  for (int nt = 0; nt < 4; ++nt) c2v[nt] = c2[colbase + nt * 16 + c16];

  const int chunk = bn * 4 + wn;
#pragma unroll
  for (int mt = 0; mt < 4; ++mt) {
#pragma unroll
    for (int r = 0; r < 4; ++r) {
      float sv[4];
#pragma unroll
      for (int nt = 0; nt < 4; ++nt) sv[nt] = 2.0f * acc[mt][nt][r] - c2v[nt];
      float m = sv[0];
      int idx = colbase + c16;
#pragma unroll
      for (int nt = 1; nt < 4; ++nt) {
        if (sv[nt] > m) { m = sv[nt]; idx = colbase + nt * 16 + c16; }
      }
      float l = 0.f;
#pragma unroll
      for (int nt = 0; nt < 4; ++nt) l += __expf(sv[nt] - m);
      for (int d = 1; d < 16; d <<= 1) {
        float om = __shfl_xor(m, d, 64);
        float ol = __shfl_xor(l, d, 64);
        int oi = __shfl_xor(idx, d, 64);
        float M = fmaxf(m, om);
        l = l * __expf(m - M) + ol * __expf(om - M);
        idx = (om > m || (om == m && oi < idx)) ? oi : idx;
        m = M;
      }
      if (c16 == 0) {
        const int row = bmBase + wm * 64 + mt * 16 + quad * 4 + r;
        pm[(size_t)row * NCHUNK + chunk] = m;
        pl[(size_t)row * NCHUNK + chunk] = l;
        pidx[(size_t)row * NCHUNK + chunk] = idx;
      }
    }
  }
}

// ---------- K2: per-row combine — single wave, 2 chunks/lane, no LDS ----------
__global__ __launch_bounds__(64) void combine_kernel(
    const float* __restrict__ pm, const float* __restrict__ pl,
    const int* __restrict__ pidx, const float* __restrict__ x,
    const float* __restrict__ cent, const float* __restrict__ c2,
    const int* __restrict__ y,
    float* __restrict__ loss_part, float* __restrict__ corr_part) {
  const int row = blockIdx.x, t = threadIdx.x;  // t = lane, 0..63
  const int yc = y[row];
  const size_t base = (size_t)row * NCHUNK;

  const float m0 = pm[base + t],      l0 = pl[base + t];
  const float m1 = pm[base + t + 64], l1 = pl[base + t + 64];
  const int   i0 = pidx[base + t],    i1 = pidx[base + t + 64];
  float m = fmaxf(m0, m1);
  float l = l0 * __expf(m0 - m) + l1 * __expf(m1 - m);
  int idx = (m1 > m0) ? i1 : i0;     // tie keeps lower index (i0 < i1 always)

  const float4* xa = (const float4*)(x + (size_t)row * KDIM) + t * 4;
  const float4* ca = (const float4*)(cent + (size_t)yc * KDIM) + t * 4;
  float dot = 0.f;
#pragma unroll
  for (int j = 0; j < 4; ++j) {
    const float4 a = xa[j], b = ca[j];
    dot += a.x * b.x + a.y * b.y + a.z * b.z + a.w * b.w;
  }

  for (int d = 1; d < 64; d <<= 1) {
    const float om = __shfl_xor(m, d, 64);
    const float ol = __shfl_xor(l, d, 64);
    const int oi = __shfl_xor(idx, d, 64);
    const float od = __shfl_xor(dot, d, 64);
    const float M = fmaxf(m, om);
    l = l * __expf(m - M) + ol * __expf(om - M);
    idx = (om > m || (om == m && oi < idx)) ? oi : idx;
    m = M;
    dot += od;
  }
  if (t == 0) {
    const float sy = 2.0f * dot - c2[yc];
    loss_part[row] = __logf(l) + m - sy;
    corr_part[row] = (idx == yc) ? 1.f : 0.f;
  }
}

// ---------- K3: finalize means ----------
__global__ __launch_bounds__(256) void finalize(const float* __restrict__ loss_part,
                                                const float* __restrict__ corr_part,
                                                float* __restrict__ out) {
  const int t = threadIdx.x;
  float s0 = 0.f, s1 = 0.f;
  for (int i = t; i < MDIM; i += 256) { s0 += loss_part[i]; s1 += corr_part[i]; }
  for (int d = 32; d; d >>= 1) {
    s0 += __shfl_down(s0, d, 64);
    s1 += __shfl_down(s1, d, 64);
  }
  __shared__ float r0[4], r1[4];
  if ((t & 63) == 0) { r0[t >> 6] = s0; r1[t >> 6] = s1; }
  __syncthreads();
  if (t == 0) {
    out[0] = (r0[0] + r0[1] + r0[2] + r0[3]) * (1.0f / MDIM);
    out[1] = (r1[0] + r1[1] + r1[2] + r1[3]) * (1.0f / MDIM);
  }
}

// ---------- launch ----------
extern "C" void kernel_launch(void* const* d_in, const int* in_sizes, int n_in,
                              void* d_out, int out_size, void* d_ws, size_t ws_size,
                              hipStream_t stream) {
  const float* x = (const float*)d_in[0];
  const int* y = (const int*)d_in[1];
  const float* cent = (const float*)d_in[2];
  float* out = (float*)d_out;

  char* ws = (char*)d_ws;
  const size_t OFF_XB = 0;                                   // 4 MB
  const size_t OFF_CB = OFF_XB + (size_t)MDIM * KDIM * 2;    // 16 MB
  const size_t OFF_C2 = OFF_CB + (size_t)CDIM * KDIM * 2;    // 32 KB
  const size_t OFF_PM = OFF_C2 + (size_t)CDIM * 4;           // 1 MB
  const size_t OFF_PL = OFF_PM + (size_t)NCHUNK * MDIM * 4;  // 1 MB
  const size_t OFF_PI = OFF_PL + (size_t)NCHUNK * MDIM * 4;  // 1 MB
  const size_t OFF_LP = OFF_PI + (size_t)NCHUNK * MDIM * 4;  // 8 KB
  const size_t OFF_CP = OFF_LP + (size_t)MDIM * 4;           // 8 KB
  const size_t NEED = OFF_CP + (size_t)MDIM * 4;
  if (ws_size < NEED) return;

  unsigned short* xb = (unsigned short*)(ws + OFF_XB);
  unsigned short* cb = (unsigned short*)(ws + OFF_CB);
  float* c2 = (float*)(ws + OFF_C2);
  float* pm = (float*)(ws + OFF_PM);
  float* pl = (float*)(ws + OFF_PL);
  int* pidx = (int*)(ws + OFF_PI);
  float* loss_part = (float*)(ws + OFF_LP);
  float* corr_part = (float*)(ws + OFF_CP);

  convert_all<<<CVT_BLOCKS, 256, 0, stream>>>(x, cent, xb, cb, c2);
  gemm_reduce<<<dim3(CDIM / BN, MDIM / BM), 1024, 0, stream>>>(xb, cb, c2, pm, pl, pidx);
  combine_kernel<<<MDIM, 64, 0, stream>>>(pm, pl, pidx, x, cent, c2, y, loss_part, corr_part);
  finalize<<<1, 256, 0, stream>>>(loss_part, corr_part, out);
}